// Round 6
// baseline (99.755 us; speedup 1.0000x reference)
//
#include <hip/hip_runtime.h>

#define N_CLS 28
#define DIM   64
#define VB    128            // nodes per bucket
#define VB_SH 7
#define NBKT_MAX 1024
#define PBLK  64             // partition blocks (fixed tiling shared by bcnt/part)

// ---- per-(block,bucket) edge counts: plain writes, no atomics, no pre-zero ----
__global__ void __launch_bounds__(256)
k_bcnt(const int* __restrict__ dst, int* __restrict__ part, int E, int nbkt, int tile) {
    __shared__ int h[NBKT_MAX];
    int tid = threadIdx.x, b = blockIdx.x;
    for (int i = tid; i < nbkt; i += 256) h[i] = 0;
    __syncthreads();
    int s0 = b * tile, s1 = min(E, s0 + tile);
    for (int i = s0 + tid; i < s1; i += 256)
        atomicAdd(&h[dst[i] >> VB_SH], 1);          // LDS atomic only
    __syncthreads();
    for (int i = tid; i < nbkt; i += 256) part[b * nbkt + i] = h[i];
}

// ---- constants: T1 = emb@W1 (blocks 0..27); u,cc (block 28); zero out (block 29) ----
__global__ void k_const(const float* __restrict__ emb, const float* __restrict__ W1,
                        const float* __restrict__ W2, const float* __restrict__ linW,
                        const float* __restrict__ b2, const float* __restrict__ linb,
                        float* __restrict__ T1, float* __restrict__ u, float* __restrict__ cc,
                        float* __restrict__ out, int out_size) {
    int j = threadIdx.x;
    int r = blockIdx.x;
    if (r < N_CLS) {
        float acc = 0.f;
#pragma unroll
        for (int k = 0; k < DIM; ++k) acc += emb[r * DIM + k] * W1[k * DIM + j];
        T1[r * DIM + j] = acc;
    } else if (r == N_CLS) {
        float acc = 0.f;
#pragma unroll
        for (int k = 0; k < DIM; ++k) acc += W2[j * DIM + k] * linW[k];
        u[j] = acc;
        float p = b2[j] * linW[j];
#pragma unroll
        for (int off = 32; off; off >>= 1) p += __shfl_down(p, off);
        if (j == 0) cc[0] = p + linb[0];
    } else {
        for (int i = j; i < out_size; i += 64) out[i] = 0.f;
    }
}

// ---- scan over partition blocks, per bucket (coalesced: consecutive tid = consecutive bucket) ----
__global__ void __launch_bounds__(256)
k_scan1(const int* __restrict__ part, int* __restrict__ cum,
        int* __restrict__ total, int nbkt) {
    int k = blockIdx.x * 256 + threadIdx.x;
    if (k >= nbkt) return;
    int run = 0;
#pragma unroll 8
    for (int b = 0; b < PBLK; ++b) {
        int c = part[b * nbkt + k];
        cum[b * nbkt + k] = run;
        run += c;
    }
    total[k] = run;
}

// ---- exclusive scan of bucket totals -> base[0..nbkt] ----
__global__ void __launch_bounds__(1024)
k_scan2(const int* __restrict__ total, int* __restrict__ base, int nbkt) {
    __shared__ int s[1024];
    int tid = threadIdx.x;
    int v = (tid < nbkt) ? total[tid] : 0;
    s[tid] = v;
    __syncthreads();
    for (int off = 1; off < 1024; off <<= 1) {
        int a = (tid >= off) ? s[tid - off] : 0;
        __syncthreads();
        s[tid] += a;
        __syncthreads();
    }
    if (tid < nbkt) base[tid] = s[tid] - v;
    if (tid == nbkt - 1) base[nbkt] = s[tid];
}

// ---- partition: slot = base[bkt] + cum[blk][bkt] + LDS-rank. ZERO global atomics ----
__global__ void __launch_bounds__(512)
k_part(const int* __restrict__ src, const int* __restrict__ dst,
       const int* __restrict__ cum, const int* __restrict__ base,
       int* __restrict__ ebkt, int E, int nbkt, int tile) {
    __shared__ int h[NBKT_MAX];
    __shared__ int startb[NBKT_MAX];
    int tid = threadIdx.x, b = blockIdx.x;
    for (int i = tid; i < nbkt; i += 512) {
        h[i] = 0;
        startb[i] = base[i] + cum[b * nbkt + i];
    }
    __syncthreads();
    int s0 = b * tile, s1 = min(E, s0 + tile);
    for (int i = s0 + tid; i < s1; i += 512) {
        int s = src[i], d = dst[i];
        int bkt = d >> VB_SH;
        int r = atomicAdd(&h[bkt], 1);              // LDS atomic only
        ebkt[startb[bkt] + r] = s | ((d & (VB - 1)) << 17);
    }
}

// ---- per-bucket degree count in LDS -> xd = {dinv, bits(x)} ----
__global__ void __launch_bounds__(256)
k_deg(const int* __restrict__ ebkt, const int* __restrict__ base,
      const int* __restrict__ x, float2* __restrict__ xd, int N) {
    __shared__ int dg[VB];
    int tid = threadIdx.x, b = blockIdx.x;
    if (tid < VB) dg[tid] = 0;
    __syncthreads();
    int e0 = base[b], e1 = base[b + 1];
    for (int i = e0 + tid; i < e1; i += 256)
        atomicAdd(&dg[ebkt[i] >> 17], 1);
    __syncthreads();
    int v = b * VB + tid;
    if (tid < VB && v < N)
        xd[v] = make_float2(rsqrtf((float)(dg[tid] + 1)), __int_as_float(x[v]));
}

// ---- layer 1: per-bucket 128x28 weighted class histogram in LDS, then h1 -> t ----
__global__ void __launch_bounds__(256)
k_l1(const int* __restrict__ ebkt, const int* __restrict__ base,
     const float2* __restrict__ xd, const float* __restrict__ T1,
     const float* __restrict__ b1, const float* __restrict__ u,
     float* __restrict__ t, int N) {
    __shared__ __align__(16) float cnt[VB * N_CLS];   // 14336 B
    __shared__ float T1s[N_CLS * DIM];                // 7168 B
    __shared__ float b1s[DIM], us[DIM];
    int tid = threadIdx.x, b = blockIdx.x;
    for (int i = tid; i < VB * N_CLS; i += 256) cnt[i] = 0.f;
    for (int i = tid; i < N_CLS * DIM; i += 256) T1s[i] = T1[i];
    if (tid < DIM) { b1s[tid] = b1[tid]; us[tid] = u[tid]; }
    __syncthreads();
    int e0 = base[b], e1 = base[b + 1];
    for (int i = e0 + tid; i < e1; i += 256) {
        int p = ebkt[i];
        float2 xs = xd[p & 0x1FFFF];                  // 8B L2 gather
        atomicAdd(&cnt[(p >> 17) * N_CLS + __float_as_int(xs.y)], xs.x);
    }
    __syncthreads();
    int wave = tid >> 6, lane = tid & 63;
    float tc[N_CLS];
#pragma unroll
    for (int c = 0; c < N_CLS; ++c) tc[c] = T1s[c * DIM + lane]; // T1 column in regs
    int v0 = b * VB;
#pragma unroll 4
    for (int it = 0; it < VB / 4; ++it) {
        int lv = wave * (VB / 4) + it;
        int v = v0 + lv;
        if (v >= N) break;
        float2 pv = xd[v];
        float dv = pv.x;
        int xv = __float_as_int(pv.y);
        const float4* row = (const float4*)&cnt[lv * N_CLS]; // uniform-addr reads
        float acc = dv * T1s[xv * DIM + lane];               // self-loop
#pragma unroll
        for (int q4 = 0; q4 < 7; ++q4) {
            float4 r = row[q4];
            acc += r.x * tc[q4 * 4 + 0] + r.y * tc[q4 * 4 + 1]
                 + r.z * tc[q4 * 4 + 2] + r.w * tc[q4 * 4 + 3];
        }
        float hh = fmaxf(dv * acc + b1s[lane], 0.f);
        float q = hh * us[lane];
#pragma unroll
        for (int off = 32; off; off >>= 1) q += __shfl_down(q, off);
        if (lane == 0) t[v] = dv * q;
    }
}

// ---- layer 2 + readout: per-bucket LDS accumulate of t[src], LDS graph bins ----
__global__ void __launch_bounds__(256)
k_l2(const int* __restrict__ ebkt, const int* __restrict__ base,
     const float2* __restrict__ xd, const float* __restrict__ t,
     const float* __restrict__ cc, const int* __restrict__ batch,
     float* __restrict__ out, int N, int n_graphs) {
    __shared__ float acc[VB];
    __shared__ float og[64];
    __shared__ int g0s;
    int tid = threadIdx.x, b = blockIdx.x;
    if (tid < VB) acc[tid] = 0.f;
    if (tid < 64) og[tid] = 0.f;
    if (tid == 0) g0s = batch[b * VB];
    __syncthreads();
    int e0 = base[b], e1 = base[b + 1];
    for (int i = e0 + tid; i < e1; i += 256) {
        int p = ebkt[i];
        atomicAdd(&acc[p >> 17], t[p & 0x1FFFF]);
    }
    __syncthreads();
    int v = b * VB + tid;
    if (tid < VB && v < N) {
        float y = xd[v].x * (acc[tid] + t[v]) + cc[0];
        int g = batch[v];
        int off = g - g0s;                 // batch sorted -> off >= 0, small span
        if (off < 64) atomicAdd(&og[off], y);
        else atomicAdd(&out[g], y);
    }
    __syncthreads();
    if (tid < 64) {
        float val = og[tid];
        int g = g0s + tid;
        if (val != 0.f && g < n_graphs) atomicAdd(&out[g], val);
    }
}

extern "C" void kernel_launch(void* const* d_in, const int* in_sizes, int n_in,
                              void* d_out, int out_size, void* d_ws, size_t ws_size,
                              hipStream_t stream) {
    const int*   x     = (const int*)d_in[0];
    const int*   ei    = (const int*)d_in[1];
    const int*   batch = (const int*)d_in[3];
    const float* emb   = (const float*)d_in[4];
    const float* W1    = (const float*)d_in[5];
    const float* b1    = (const float*)d_in[6];
    const float* W2    = (const float*)d_in[7];
    const float* b2    = (const float*)d_in[8];
    const float* linW  = (const float*)d_in[9];
    const float* linb  = (const float*)d_in[10];

    const int N = in_sizes[0];
    const int E = in_sizes[1] / 2;
    const int* srcp = ei;
    const int* dstp = ei + E;
    float* out = (float*)d_out;

    const int nbkt = (N + VB - 1) >> VB_SH;         // 782 for N=100000
    const int tile = (E + PBLK - 1) / PBLK;

    char* w = (char*)d_ws;
    float2* xd    = (float2*)w; w += (size_t)N * 8;
    float*  t     = (float*)w;  w += (size_t)N * 4;
    int*    ebkt  = (int*)w;    w += ((size_t)E * 4 + 15) & ~15ULL;
    int*    part  = (int*)w;    w += (size_t)PBLK * nbkt * 4;
    int*    cum   = (int*)w;    w += (size_t)PBLK * nbkt * 4;
    int*    total = (int*)w;    w += (size_t)NBKT_MAX * 4;
    int*    base  = (int*)w;    w += (size_t)(NBKT_MAX + 4) * 4;
    float*  T1    = (float*)w;  w += (size_t)N_CLS * DIM * 4;
    float*  u     = (float*)w;  w += DIM * 4;
    float*  cc    = (float*)w;  w += 16;

    k_const<<<N_CLS + 2, 64, 0, stream>>>(emb, W1, W2, linW, b2, linb, T1, u, cc,
                                          out, out_size);
    k_bcnt <<<PBLK, 256, 0, stream>>>(dstp, part, E, nbkt, tile);
    k_scan1<<<(nbkt + 255) / 256, 256, 0, stream>>>(part, cum, total, nbkt);
    k_scan2<<<1, 1024, 0, stream>>>(total, base, nbkt);
    k_part <<<PBLK, 512, 0, stream>>>(srcp, dstp, cum, base, ebkt, E, nbkt, tile);
    k_deg  <<<nbkt, 256, 0, stream>>>(ebkt, base, x, xd, N);
    k_l1   <<<nbkt, 256, 0, stream>>>(ebkt, base, xd, T1, b1, u, t, N);
    k_l2   <<<nbkt, 256, 0, stream>>>(ebkt, base, xd, t, cc, batch, out, N, out_size);
}